// Round 2
// baseline (197.502 us; speedup 1.0000x reference)
//
#include <hip/hip_runtime.h>

// MSE_DQ_FK: dual-quaternion denorm -> local rot -> FK -> mse losses -> scalar.
// B=64, T=1024, J=22, C=176. Layout (B,C,T), T contiguous -> thread-per-t
// gives coalesced 256B/wave loads. Only rotation quats (4 of 8 dq channels)
// are read. Telescoping identity: global rot[j] = conj(q0n) * qjn (local[0]
// forced identity + unit-norm cancellation); ik/dec roots are identity.
//
// Round-4 structure:
//  * ROLE SPLIT: each (b,t) handled by two threads of one 512-thread block.
//    role 0: {ik, tgt} streams -> EE losses (joints 4,8,13,17,21)
//    role 1: {dec, ik} streams -> regularizer losses (16 non-sparse joints)
//    2 streams/thread instead of 3 -> 8 waves/CU = 2 waves/SIMD (vs 1 for
//    the plain 256-block launch) hides vmcnt stalls; ik double-read hits
//    L1/L2 (same CU), HBM fetch unchanged.
//  * __launch_bounds__(512, 1): round-3's (512,2) clamped the allocator to
//    128 VGPR (4 waves/SIMD target) -> 45 MB of scratch spill traffic
//    (WRITE_SIZE counter) and a 3.5x slowdown. The grid is 256 blocks on
//    256 CUs, so only 1 block/CU resides regardless; (512,1) keeps the
//    2-waves/SIMD occupancy while allowing ~200 VGPR, no spill.
//  * UNIT-QUAT FROBENIUS IDENTITY: ||R(a)-R(b)||_F^2 = 8*(1 - dot(a,b)^2)
//    for unit quats -> replaces 2x qmat + 27-op diff (~90 VALU) with ~10.
//  * Per-chain register prefetch pipeline retained (prefetch chain k+1
//    while computing chain k; 32-40 outstanding loads per chain).

#define T_DIM 1024

struct Q { float w, x, y, z; };
struct V3 { float x, y, z; };
struct St { Q rot; V3 pos; };

__device__ __forceinline__ Q qmul(const Q a, const Q b) {
    Q r;
    r.w = a.w*b.w - a.x*b.x - a.y*b.y - a.z*b.z;
    r.x = a.w*b.x + a.x*b.w + a.y*b.z - a.z*b.y;
    r.y = a.w*b.y - a.x*b.z + a.y*b.w + a.z*b.x;
    r.z = a.w*b.z + a.x*b.y - a.y*b.x + a.z*b.w;
    return r;
}

__device__ __forceinline__ V3 qrot(const Q q, const V3 v) {
    float tx = 2.f*(q.y*v.z - q.z*v.y);
    float ty = 2.f*(q.z*v.x - q.x*v.z);
    float tz = 2.f*(q.x*v.y - q.y*v.x);
    V3 r;
    r.x = v.x + q.w*tx + (q.y*tz - q.z*ty);
    r.y = v.y + q.w*ty + (q.z*tx - q.x*tz);
    r.z = v.z + q.w*tz + (q.x*ty - q.y*tx);
    return r;
}

// ||R(a)-R(b)||_F^2 for UNIT quaternions:
//   = 6 - 2*tr(R(a)^T R(b)) = 6 - 2*(4*dot(a,b)^2 - 1) = 8*(1 - dot(a,b)^2)
__device__ __forceinline__ float rmdiff2u(const Q a, const Q b) {
    float d = a.w*b.w + a.x*b.x + a.y*b.y + a.z*b.z;
    return 8.f*(1.f - d*d);
}

__device__ __forceinline__ float pdiff2(const V3 a, const V3 b) {
    float dx=a.x-b.x, dy=a.y-b.y, dz=a.z-b.z;
    return dx*dx+dy*dy+dz*dz;
}

__device__ __forceinline__ V3 v3add(const V3 a, const V3 b) {
    return V3{a.x+b.x, a.y+b.y, a.z+b.z};
}

// Denorm raw quat channels (c0..c0+3) then normalize. mean/stdv indexed with
// compile-time-uniform c0 -> scalar loads.
__device__ __forceinline__ Q mkq(const float r[4], const int c0,
                                 const float* __restrict__ mean,
                                 const float* __restrict__ stdv) {
    Q q;
    q.w = r[0]*stdv[c0+0] + mean[c0+0];
    q.x = r[1]*stdv[c0+1] + mean[c0+1];
    q.y = r[2]*stdv[c0+2] + mean[c0+2];
    q.z = r[3]*stdv[c0+3] + mean[c0+3];
    float inv = rsqrtf(q.w*q.w + q.x*q.x + q.y*q.y + q.z*q.z);
    q.w*=inv; q.x*=inv; q.y*=inv; q.z*=inv;
    return q;
}

// Prefetch raw channel dwords for joints J0..J0+N-1 (two streams) into
// register arrays. 8 loads/joint; chains are 4-5 joints -> 32-40 outstanding.
// Both pointers are pre-adjusted so channel base is j*8 uniformly (ik stream
// pointer is shifted by -8*T_DIM to account for its missing root joint).
template<int J0, int N>
__device__ __forceinline__ void pf2(
    const float* __restrict__ xp, const float* __restrict__ yp,
    float (*xr)[4], float (*yr)[4])
{
#pragma unroll
    for (int jj = 0; jj < N; ++jj) {
        const int j = J0 + jj;
#pragma unroll
        for (int c = 0; c < 4; ++c) {
            xr[jj][c] = xp[(j*8 + c)*T_DIM];
            yr[jj][c] = yp[(j*8 + c)*T_DIM];
        }
    }
}

// One joint step for both chains from prefetched raw data.
// PRE: premultiply Y's quat by q0c (tgt stream: non-identity root).
// LOSS: accumulate pos/rot losses at this joint.
template<int J, bool LOSS, bool PRE>
__device__ __forceinline__ void step2(
    St& sx, St& sy,
    const float xr[4], const float yr[4],
    const float* __restrict__ mean, const float* __restrict__ stdv,
    const float* __restrict__ offs, const Q q0c,
    float& ap, float& ar)
{
    const int c0 = J*8;
    Q qx = mkq(xr, c0, mean, stdv);
    Q qy = mkq(yr, c0, mean, stdv);
    if (PRE) qy = qmul(q0c, qy);
    V3 off = { offs[3*J], offs[3*J+1], offs[3*J+2] };
    V3 px = v3add(qrot(sx.rot, off), sx.pos);
    V3 py = v3add(qrot(sy.rot, off), sy.pos);
    if (LOSS) {
        ap += pdiff2(px, py);
        ar += rmdiff2u(qx, qy);
    }
    sx.rot = qx; sx.pos = px;
    sy.rot = qy; sy.pos = py;
}

// Walk all 5 chains for one stream pair with pipelined prefetch.
// EEROLE=true : X=ik, Y=tgt (PRE), losses at EE joints {4,8,13,17,21}
// EEROLE=false: X=dec, Y=ik, losses at the 16 non-sparse joints
template<bool EEROLE>
__device__ __forceinline__ void walk(
    const float* __restrict__ xp, const float* __restrict__ yp,
    const float* __restrict__ mean, const float* __restrict__ stdv,
    const float* __restrict__ offs,
    float& ap, float& ar)
{
    // PARENTS = [0,0,1,2,3, 0,5,6,7, 0,9,10,11,12, 11,14,15,16, 11,18,19,20]
    // Chains: A=1..4(EE4) B=5..8(EE8) C=9..13(EE13,branch@11) D=14..17(EE17)
    //         E=18..21(EE21)
    float Xa[4][4], Ya[4][4];
    float Xb[4][4], Yb[4][4];
    float Xc[5][4], Yc[5][4];
    float Xd[4][4], Yd[4][4];
    float Xe[4][4], Ye[4][4];
    float rq0[4];

    if (EEROLE) {
#pragma unroll
        for (int c = 0; c < 4; ++c) rq0[c] = yp[c*T_DIM];  // tgt root quat
    }
    pf2<1,4>(xp, yp, Xa, Ya);
    pf2<5,4>(xp, yp, Xb, Yb);

    Q q0c = {1.f, 0.f, 0.f, 0.f};
    if (EEROLE) {
        Q q0 = mkq(rq0, 0, mean, stdv);
        q0c = { q0.w, -q0.x, -q0.y, -q0.z };
    }
    const St root = { {1.f,0.f,0.f,0.f}, {0.f,0.f,0.f} };
    St sx, sy;

    // chain A
    sx = root; sy = root;
    step2<1, !EEROLE, EEROLE>(sx,sy, Xa[0],Ya[0], mean,stdv,offs,q0c, ap,ar);
    step2<2, !EEROLE, EEROLE>(sx,sy, Xa[1],Ya[1], mean,stdv,offs,q0c, ap,ar);
    step2<3, !EEROLE, EEROLE>(sx,sy, Xa[2],Ya[2], mean,stdv,offs,q0c, ap,ar);
    step2<4,  EEROLE, EEROLE>(sx,sy, Xa[3],Ya[3], mean,stdv,offs,q0c, ap,ar);

    pf2<9,5>(xp, yp, Xc, Yc);

    // chain B
    sx = root; sy = root;
    step2<5, !EEROLE, EEROLE>(sx,sy, Xb[0],Yb[0], mean,stdv,offs,q0c, ap,ar);
    step2<6, !EEROLE, EEROLE>(sx,sy, Xb[1],Yb[1], mean,stdv,offs,q0c, ap,ar);
    step2<7, !EEROLE, EEROLE>(sx,sy, Xb[2],Yb[2], mean,stdv,offs,q0c, ap,ar);
    step2<8,  EEROLE, EEROLE>(sx,sy, Xb[3],Yb[3], mean,stdv,offs,q0c, ap,ar);

    pf2<14,4>(xp, yp, Xd, Yd);

    // chain C: 9-10-11 (branch point 11), then 12-13
    sx = root; sy = root;
    step2<9,  !EEROLE, EEROLE>(sx,sy, Xc[0],Yc[0], mean,stdv,offs,q0c, ap,ar);
    step2<10, !EEROLE, EEROLE>(sx,sy, Xc[1],Yc[1], mean,stdv,offs,q0c, ap,ar);
    step2<11, !EEROLE, EEROLE>(sx,sy, Xc[2],Yc[2], mean,stdv,offs,q0c, ap,ar);
    const St sx11 = sx, sy11 = sy;
    step2<12, !EEROLE, EEROLE>(sx,sy, Xc[3],Yc[3], mean,stdv,offs,q0c, ap,ar);
    step2<13,  EEROLE, EEROLE>(sx,sy, Xc[4],Yc[4], mean,stdv,offs,q0c, ap,ar);

    pf2<18,4>(xp, yp, Xe, Ye);

    // chain D: 14-17 from branch point
    sx = sx11; sy = sy11;
    step2<14, !EEROLE, EEROLE>(sx,sy, Xd[0],Yd[0], mean,stdv,offs,q0c, ap,ar);
    step2<15, !EEROLE, EEROLE>(sx,sy, Xd[1],Yd[1], mean,stdv,offs,q0c, ap,ar);
    step2<16, !EEROLE, EEROLE>(sx,sy, Xd[2],Yd[2], mean,stdv,offs,q0c, ap,ar);
    step2<17,  EEROLE, EEROLE>(sx,sy, Xd[3],Yd[3], mean,stdv,offs,q0c, ap,ar);

    // chain E: 18-21 from branch point
    sx = sx11; sy = sy11;
    step2<18, !EEROLE, EEROLE>(sx,sy, Xe[0],Ye[0], mean,stdv,offs,q0c, ap,ar);
    step2<19, !EEROLE, EEROLE>(sx,sy, Xe[1],Ye[1], mean,stdv,offs,q0c, ap,ar);
    step2<20, !EEROLE, EEROLE>(sx,sy, Xe[2],Ye[2], mean,stdv,offs,q0c, ap,ar);
    step2<21,  EEROLE, EEROLE>(sx,sy, Xe[3],Ye[3], mean,stdv,offs,q0c, ap,ar);
}

__global__ __launch_bounds__(512, 1) void fk_loss_kernel(
    const float* __restrict__ ik, const float* __restrict__ dec,
    const float* __restrict__ tgt, const float* __restrict__ mean,
    const float* __restrict__ stdv, const float* __restrict__ offs,
    float* __restrict__ out)
{
    __shared__ float swred[8];
    const int tid = threadIdx.x;
    const int role = tid >> 8;       // waves 0-3: EE role, waves 4-7: REG role
    const int lt = tid & 255;
    const int p = blockIdx.x * 256 + lt;
    const int b = p >> 10;           // / T
    const int t = p & 1023;          // % T
    // ik pointer pre-shifted by -8*T_DIM: its array lacks the root joint, so
    // channel base becomes j*8 uniformly (only dereferenced for j >= 1).
    const float* ikp = ik  + (size_t)b * (168*1024) + t - (size_t)(8*T_DIM);
    const float* dep = dec + (size_t)b * (176*1024) + t;
    const float* tgp = tgt + (size_t)b * (176*1024) + t;

    float ap = 0.f, ar = 0.f;
    float loss;
    const float BT = 65536.f;
    if (role == 0) {
        // loss_ee = ee_pos/(B*T*5*3) + ee_rm/(B*T*5*9)
        walk<true>(ikp, tgp, mean, stdv, offs, ap, ar);
        loss = ap * (1.0f/(BT*15.f)) + ar * (1.0f/(BT*45.f));
    } else {
        // loss_reg = 0.1*( reg_pos/(B*T*16*3) + reg_rm/(B*T*16*9) )
        walk<false>(dep, ikp, mean, stdv, offs, ap, ar);
        loss = ap * (0.1f/(BT*48.f)) + ar * (0.1f/(BT*144.f));
    }

    // wave(64) shuffle reduce -> cross-wave via LDS -> one atomic per block
#pragma unroll
    for (int o = 32; o > 0; o >>= 1) loss += __shfl_down(loss, o);
    if ((tid & 63) == 0) swred[tid >> 6] = loss;
    __syncthreads();
    if (tid == 0) {
        float s = 0.f;
#pragma unroll
        for (int i = 0; i < 8; ++i) s += swred[i];
        atomicAdd(out, s);
    }
}

extern "C" void kernel_launch(void* const* d_in, const int* in_sizes, int n_in,
                              void* d_out, int out_size, void* d_ws, size_t ws_size,
                              hipStream_t stream) {
    // inputs (setup_inputs order): input(unused), input_ik, input_decoder,
    // target, mean_dqs, std_dqs, offsets
    const float* ikx  = (const float*)d_in[1];
    const float* dec  = (const float*)d_in[2];
    const float* tgt  = (const float*)d_in[3];
    const float* mean = (const float*)d_in[4];
    const float* stdv = (const float*)d_in[5];
    const float* offs = (const float*)d_in[6];
    float* out = (float*)d_out;

    hipMemsetAsync(out, 0, sizeof(float), stream);
    // 64*1024 poses, 2 role-threads each / 512 threads = 256 blocks
    // (1 block/CU, 8 waves/CU = 2 waves/SIMD)
    fk_loss_kernel<<<256, 512, 0, stream>>>(ikx, dec, tgt, mean, stdv, offs, out);
}

// Round 3
// 179.956 us; speedup vs baseline: 1.0975x; 1.0975x over previous
//
#include <hip/hip_runtime.h>

// MSE_DQ_FK: dual-quaternion denorm -> local rot -> FK -> mse losses -> scalar.
// B=64, T=1024, J=22, C=176. Layout (B,C,T), T contiguous -> thread-per-t
// gives coalesced 256B/wave loads. Only rotation quats (4 of 8 dq channels)
// are read. Telescoping identity: global rot[j] = conj(q0n) * qjn (local[0]
// forced identity + unit-norm cancellation); ik/dec roots are identity.
//
// Round-5 structure: CHAIN-PARALLEL decomposition.
//   Rounds 3-4 post-mortem: a (role x all-chains) 512-thread kernel needs
//   ~125 live VGPRs; the allocator caps 512-thread blocks at 128 VGPR
//   regardless of __launch_bounds__ min-waves arg (measured: (512,2) and
//   (512,1) both -> VGPR_Count=128, WRITE_SIZE=44MB scratch spill, 57us).
//   Fix: shrink the per-thread working set, not the budget.
//   One 256-thread block = (role, chain, 256 poses):
//     role 0: {ik, tgt} streams -> EE loss at the chain's end-effector
//     role 1: {dec, ik} streams -> REG loss at the chain's non-sparse joints
//     chains: A=1..4  B=5..8  C=9..13  D=[9,10,11]+14..17  E=[9,10,11]+18..21
//   D/E recompute the 3-joint prefix with loss disabled (C owns its loss).
//   Per-thread live set: <=7 joints x 2 streams x 4 ch = 56 prefetch floats
//   + 14 FK state -> ~100 VGPR, no spill, all loads issued up-front
//   (<=60 outstanding, under the vmcnt=63 limit).
//   Grid 2560 blocks -> 4 resident blocks/CU (16 waves/CU, 2x round-4).
//   XCD-aware bid mapping co-locates the 10 (role,chain) blocks of a pose
//   range on one XCD back-to-back, so ik double-reads and the 9-11 prefix
//   triple-reads hit that XCD's L2 instead of refetching HBM.
//  * UNIT-QUAT FROBENIUS IDENTITY: ||R(a)-R(b)||_F^2 = 8*(1 - dot(a,b)^2).

#define T_DIM 1024

struct Q { float w, x, y, z; };
struct V3 { float x, y, z; };
struct St { Q rot; V3 pos; };

__device__ __forceinline__ Q qmul(const Q a, const Q b) {
    Q r;
    r.w = a.w*b.w - a.x*b.x - a.y*b.y - a.z*b.z;
    r.x = a.w*b.x + a.x*b.w + a.y*b.z - a.z*b.y;
    r.y = a.w*b.y - a.x*b.z + a.y*b.w + a.z*b.x;
    r.z = a.w*b.z + a.x*b.y - a.y*b.x + a.z*b.w;
    return r;
}

__device__ __forceinline__ V3 qrot(const Q q, const V3 v) {
    float tx = 2.f*(q.y*v.z - q.z*v.y);
    float ty = 2.f*(q.z*v.x - q.x*v.z);
    float tz = 2.f*(q.x*v.y - q.y*v.x);
    V3 r;
    r.x = v.x + q.w*tx + (q.y*tz - q.z*ty);
    r.y = v.y + q.w*ty + (q.z*tx - q.x*tz);
    r.z = v.z + q.w*tz + (q.x*ty - q.y*tx);
    return r;
}

// ||R(a)-R(b)||_F^2 for UNIT quaternions:
//   = 6 - 2*tr(R(a)^T R(b)) = 6 - 2*(4*dot(a,b)^2 - 1) = 8*(1 - dot(a,b)^2)
__device__ __forceinline__ float rmdiff2u(const Q a, const Q b) {
    float d = a.w*b.w + a.x*b.x + a.y*b.y + a.z*b.z;
    return 8.f*(1.f - d*d);
}

__device__ __forceinline__ float pdiff2(const V3 a, const V3 b) {
    float dx=a.x-b.x, dy=a.y-b.y, dz=a.z-b.z;
    return dx*dx+dy*dy+dz*dz;
}

__device__ __forceinline__ V3 v3add(const V3 a, const V3 b) {
    return V3{a.x+b.x, a.y+b.y, a.z+b.z};
}

// Denorm raw quat channels (c0..c0+3) then normalize. After full unroll the
// channel base is a literal -> mean/stdv accesses become s_loads.
__device__ __forceinline__ Q mkq(const float r[4], const int c0,
                                 const float* __restrict__ mean,
                                 const float* __restrict__ stdv) {
    Q q;
    q.w = r[0]*stdv[c0+0] + mean[c0+0];
    q.x = r[1]*stdv[c0+1] + mean[c0+1];
    q.y = r[2]*stdv[c0+2] + mean[c0+2];
    q.z = r[3]*stdv[c0+3] + mean[c0+3];
    float inv = rsqrtf(q.w*q.w + q.x*q.x + q.y*q.y + q.z*q.z);
    q.w*=inv; q.x*=inv; q.y*=inv; q.z*=inv;
    return q;
}

// Load raw quat channels of joint j for both streams (4 coalesced dwords ea).
// Pointers are pre-adjusted so channel base is j*8 uniformly (ik stream
// pointer shifted by -8*T_DIM: its array lacks the root joint; j >= 1 always).
__device__ __forceinline__ void pfj(
    const float* __restrict__ xp, const float* __restrict__ yp,
    const int j, float xr[4], float yr[4])
{
#pragma unroll
    for (int c = 0; c < 4; ++c) {
        xr[c] = xp[(j*8 + c)*T_DIM];
        yr[c] = yp[(j*8 + c)*T_DIM];
    }
}

// One joint step for both streams from prefetched raw data.
// pre : premultiply Y's quat by q0c (tgt stream: non-identity root).
// loss: accumulate pos/rot losses at this joint.
// All control args are compile-time-foldable after unroll.
__device__ __forceinline__ void step2(
    St& sx, St& sy,
    const float xr[4], const float yr[4], const int j,
    const bool loss, const bool pre,
    const float* __restrict__ mean, const float* __restrict__ stdv,
    const float* __restrict__ offs, const Q q0c,
    float& ap, float& ar)
{
    const int c0 = j*8;
    Q qx = mkq(xr, c0, mean, stdv);
    Q qy = mkq(yr, c0, mean, stdv);
    if (pre) qy = qmul(q0c, qy);
    V3 off = { offs[3*j], offs[3*j+1], offs[3*j+2] };
    V3 px = v3add(qrot(sx.rot, off), sx.pos);
    V3 py = v3add(qrot(sy.rot, off), sy.pos);
    if (loss) {
        ap += pdiff2(px, py);
        ar += rmdiff2u(qx, qy);
    }
    sx.rot = qx; sx.pos = px;
    sy.rot = qy; sy.pos = py;
}

// Walk ONE chain for one stream pair. All loads issued up-front.
// EEROLE=true : X=ik, Y=tgt (root premult), loss at chain end only.
// EEROLE=false: X=dec, Y=ik, loss at every chain joint except the end.
// CH: 0:A=1..4  1:B=5..8  2:C=9..13  3:D=prefix+14..17  4:E=prefix+18..21
// Prefix joints (9,10,11) never accumulate loss here (chain C owns them).
template<bool EEROLE, int CH>
__device__ __forceinline__ void chainwalk(
    const float* __restrict__ xp, const float* __restrict__ yp,
    const float* __restrict__ mean, const float* __restrict__ stdv,
    const float* __restrict__ offs,
    float& ap, float& ar)
{
    constexpr int  J0  = (CH==0)?1 : (CH==1)?5 : (CH==2)?9 : (CH==3)?14 : 18;
    constexpr int  N   = (CH==2)?5 : 4;
    constexpr bool PFX = (CH>=3);

    float rq0[4];
    float Xp[3][4], Yp[3][4];
    float X[5][4],  Y[5][4];

    // issue every load first: root (EE) + prefix + chain = <=60 outstanding
    if (EEROLE) {
#pragma unroll
        for (int c = 0; c < 4; ++c) rq0[c] = yp[c*T_DIM];  // tgt root quat
    }
    if (PFX) {
#pragma unroll
        for (int i = 0; i < 3; ++i) pfj(xp, yp, 9+i, Xp[i], Yp[i]);
    }
#pragma unroll
    for (int i = 0; i < N; ++i) pfj(xp, yp, J0+i, X[i], Y[i]);

    Q q0c = {1.f, 0.f, 0.f, 0.f};
    if (EEROLE) {
        Q q0 = mkq(rq0, 0, mean, stdv);
        q0c = { q0.w, -q0.x, -q0.y, -q0.z };
    }

    St sx = { {1.f,0.f,0.f,0.f}, {0.f,0.f,0.f} };
    St sy = sx;

    if (PFX) {
#pragma unroll
        for (int i = 0; i < 3; ++i)
            step2(sx, sy, Xp[i], Yp[i], 9+i, false, EEROLE,
                  mean, stdv, offs, q0c, ap, ar);
    }
#pragma unroll
    for (int i = 0; i < N; ++i) {
        const bool loss = EEROLE ? (i == N-1) : (i != N-1);
        step2(sx, sy, X[i], Y[i], J0+i, loss, EEROLE,
              mean, stdv, offs, q0c, ap, ar);
    }
}

__global__ __launch_bounds__(256) void fk_loss_kernel(
    const float* __restrict__ ik, const float* __restrict__ dec,
    const float* __restrict__ tgt, const float* __restrict__ mean,
    const float* __restrict__ stdv, const float* __restrict__ offs,
    float* __restrict__ out)
{
    __shared__ float swred[4];
    const int tid = threadIdx.x;

    // XCD-aware decode: HW round-robins consecutive blockIdx across the 8
    // XCDs (bid & 7). Give each XCD a contiguous range of 32 pose-blocks and
    // make the 10 (role,chain) sub-blocks of one pose-block consecutive in
    // that XCD's dispatch order -> they run near-concurrently, sharing L2
    // (ik is read by both roles, the 9-11 prefix by chains C/D/E).
    const int bid  = blockIdx.x;
    const int xcd  = bid & 7;
    const int idx  = bid >> 3;           // 0..319 within this XCD
    const int pb   = idx / 10;           // 0..31
    const int sub  = idx - pb*10;        // 0..9
    const int pose_blk = xcd*32 + pb;    // 0..255
    const int role  = (sub >= 5) ? 1 : 0;
    const int chain = sub - role*5;

    const int p = pose_blk*256 + tid;
    const int b = p >> 10;               // / T
    const int t = p & 1023;              // % T
    // ik pointer pre-shifted by -8*T_DIM (array lacks the root joint).
    const float* ikp = ik  + (size_t)b * (168*1024) + t - (size_t)(8*T_DIM);
    const float* dep = dec + (size_t)b * (176*1024) + t;
    const float* tgp = tgt + (size_t)b * (176*1024) + t;

    float ap = 0.f, ar = 0.f;
    float loss;
    const float BT = 65536.f;
    if (role == 0) {
        // loss_ee = ee_pos/(B*T*5*3) + ee_rm/(B*T*5*9)
        switch (chain) {
            case 0: chainwalk<true,0>(ikp, tgp, mean, stdv, offs, ap, ar); break;
            case 1: chainwalk<true,1>(ikp, tgp, mean, stdv, offs, ap, ar); break;
            case 2: chainwalk<true,2>(ikp, tgp, mean, stdv, offs, ap, ar); break;
            case 3: chainwalk<true,3>(ikp, tgp, mean, stdv, offs, ap, ar); break;
            default: chainwalk<true,4>(ikp, tgp, mean, stdv, offs, ap, ar); break;
        }
        loss = ap * (1.0f/(BT*15.f)) + ar * (1.0f/(BT*45.f));
    } else {
        // loss_reg = 0.1*( reg_pos/(B*T*16*3) + reg_rm/(B*T*16*9) )
        switch (chain) {
            case 0: chainwalk<false,0>(dep, ikp, mean, stdv, offs, ap, ar); break;
            case 1: chainwalk<false,1>(dep, ikp, mean, stdv, offs, ap, ar); break;
            case 2: chainwalk<false,2>(dep, ikp, mean, stdv, offs, ap, ar); break;
            case 3: chainwalk<false,3>(dep, ikp, mean, stdv, offs, ap, ar); break;
            default: chainwalk<false,4>(dep, ikp, mean, stdv, offs, ap, ar); break;
        }
        loss = ap * (0.1f/(BT*48.f)) + ar * (0.1f/(BT*144.f));
    }

    // wave(64) shuffle reduce -> cross-wave via LDS -> one atomic per block
#pragma unroll
    for (int o = 32; o > 0; o >>= 1) loss += __shfl_down(loss, o);
    if ((tid & 63) == 0) swred[tid >> 6] = loss;
    __syncthreads();
    if (tid == 0) {
        atomicAdd(out, swred[0]+swred[1]+swred[2]+swred[3]);
    }
}

extern "C" void kernel_launch(void* const* d_in, const int* in_sizes, int n_in,
                              void* d_out, int out_size, void* d_ws, size_t ws_size,
                              hipStream_t stream) {
    // inputs (setup_inputs order): input(unused), input_ik, input_decoder,
    // target, mean_dqs, std_dqs, offsets
    const float* ikx  = (const float*)d_in[1];
    const float* dec  = (const float*)d_in[2];
    const float* tgt  = (const float*)d_in[3];
    const float* mean = (const float*)d_in[4];
    const float* stdv = (const float*)d_in[5];
    const float* offs = (const float*)d_in[6];
    float* out = (float*)d_out;

    hipMemsetAsync(out, 0, sizeof(float), stream);
    // 256 pose-blocks x 2 roles x 5 chains = 2560 blocks of 256 threads
    // (4 resident blocks/CU at <=128 VGPR -> 16 waves/CU)
    fk_loss_kernel<<<2560, 256, 0, stream>>>(ikx, dec, tgt, mean, stdv, offs, out);
}